// Round 1
// baseline (289.042 us; speedup 1.0000x reference)
//
#include <hip/hip_runtime.h>
#include <hip/hip_bf16.h>
#include <stdint.h>

typedef __bf16 bf16;
typedef __bf16 bf16x4 __attribute__((ext_vector_type(4)));
typedef __bf16 bf16x8 __attribute__((ext_vector_type(8)));
typedef float  f32x4  __attribute__((ext_vector_type(4)));

#define MFMA16(a,b,c) __builtin_amdgcn_mfma_f32_16x16x32_bf16((a),(b),(c),0,0,0)

#define TSEQ 2048
#define NE   1024
#define NH   16
#define HD   64
#define MTOK 4096   // BATCH*TSEQ

// async global->LDS, 16B per lane; LDS dest = wave-uniform base + lane*16
__device__ __forceinline__ void gl_lds16(const bf16* g, bf16* l) {
  __builtin_amdgcn_global_load_lds(
      (const __attribute__((address_space(1))) void*)g,
      (__attribute__((address_space(3))) void*)l,
      16, 0, 0);
}

// ---------------- cast f32 -> bf16 (vectorized) ----------------
__global__ void k_cast(const float* __restrict__ in, bf16* __restrict__ out, int n4) {
  int i = blockIdx.x * blockDim.x + threadIdx.x;
  if (i < n4) {
    float4 v = reinterpret_cast<const float4*>(in)[i];
    bf16x4 o = { (bf16)v.x, (bf16)v.y, (bf16)v.z, (bf16)v.w };
    reinterpret_cast<bf16x4*>(out)[i] = o;
  }
}

// ---------------- transpose + cast: out[c][r] = in[r][c], in is R x C f32 ----------------
__global__ void k_transpose_cast(const float* __restrict__ in, bf16* __restrict__ out,
                                 int R, int C) {
  __shared__ float tile[64][65];
  const int r0 = blockIdx.y * 64, c0 = blockIdx.x * 64;
  const int lc = threadIdx.x & 63, lr0 = threadIdx.x >> 6;
#pragma unroll
  for (int i = 0; i < 16; ++i) {
    int lr = i*4 + lr0;
    tile[lr][lc] = in[(size_t)(r0 + lr) * C + (c0 + lc)];
  }
  __syncthreads();
#pragma unroll
  for (int i = 0; i < 16; ++i) {
    int lr = i*4 + lr0;
    out[(size_t)(c0 + lr) * R + (r0 + lc)] = (bf16)tile[lc][lr];
  }
}

// ---------------- V [b*T+t][h*64+d] -> Vt [b][h][d][t] (bf16) ----------------
__global__ void k_transpose_v(const bf16* __restrict__ V, bf16* __restrict__ Vt) {
  __shared__ bf16 tile[64][65];
  const int b = blockIdx.z, h = blockIdx.y, t0 = blockIdx.x * 64;
  const int lc = threadIdx.x & 63, lr0 = threadIdx.x >> 6;
#pragma unroll
  for (int i = 0; i < 16; ++i) {
    int lr = i*4 + lr0;  // t within tile
    tile[lr][lc] = V[(size_t)(b*TSEQ + t0 + lr)*NE + h*HD + lc];
  }
  __syncthreads();
#pragma unroll
  for (int i = 0; i < 16; ++i) {
    int lr = i*4 + lr0;  // d within head
    Vt[((size_t)(b*NH + h)*HD + lr)*TSEQ + t0 + lc] = tile[lc][lr];
  }
}

// ---------------- GEMM: C[M,N] = A[M,K] * Bt[N,K]^T, bf16 in, OutT out ----------------
// 128x128 tile, 4 waves (each 64x64 = 4x4 MFMA frags), BK=32, global_load_lds(16),
// XOR-swizzled LDS (key = (row>>1)&3 on 16B chunks) for conflict-light ds_read_b128.
template<typename OutT>
__global__ __launch_bounds__(256) void k_gemm_bt(const bf16* __restrict__ A,
                                                 const bf16* __restrict__ Bt,
                                                 OutT* __restrict__ C,
                                                 const int M, const int N, const int K) {
  __shared__ bf16 As[128*32];
  __shared__ bf16 Bs[128*32];
  const int tid  = threadIdx.x;
  const int lane = tid & 63;
  const int wave = tid >> 6;
  const int wr = (wave >> 1) * 64;
  const int wc = (wave & 1) * 64;
  const int l15 = lane & 15;
  const int l4  = lane >> 4;
  const int bm = blockIdx.y * 128;
  const int bn = blockIdx.x * 128;

  // staging: thread t fills LDS bytes [t*16, t*16+16) per 4KB half (row=t>>2, col16=t&3),
  // global source column pre-swizzled with the same XOR used on reads.
  const int srow = tid >> 2;                              // 0..63
  const int scol = ((tid & 3) ^ ((tid >> 3) & 3)) * 8;    // swizzled element column
  const bf16* ag = A  + (size_t)(bm + srow) * K + scol;
  const bf16* bg = Bt + (size_t)(bn + srow) * K + scol;
  bf16* al = As + tid * 8;
  bf16* bl = Bs + tid * 8;
  const size_t half = (size_t)64 * K;

  const int kx = (l4 ^ ((l15 >> 1) & 3)) * 8;  // swizzled k-chunk for fragment reads

  f32x4 acc[4][4] = {};

  for (int k0 = 0; k0 < K; k0 += 32) {
    __syncthreads();
    gl_lds16(ag + k0,        al);
    gl_lds16(ag + k0 + half, al + 64*32);
    gl_lds16(bg + k0,        bl);
    gl_lds16(bg + k0 + half, bl + 64*32);
    __syncthreads();

    bf16x8 af[4], bfr[4];
#pragma unroll
    for (int m = 0; m < 4; ++m)
      af[m] = *reinterpret_cast<const bf16x8*>(&As[(wr + m*16 + l15)*32 + kx]);
#pragma unroll
    for (int n = 0; n < 4; ++n)
      bfr[n] = *reinterpret_cast<const bf16x8*>(&Bs[(wc + n*16 + l15)*32 + kx]);
#pragma unroll
    for (int m = 0; m < 4; ++m)
#pragma unroll
      for (int n = 0; n < 4; ++n)
        acc[m][n] = MFMA16(af[m], bfr[n], acc[m][n]);
  }

#pragma unroll
  for (int m = 0; m < 4; ++m) {
    const int row = bm + wr + m*16 + l4*4;
#pragma unroll
    for (int n = 0; n < 4; ++n) {
      const int col = bn + wc + n*16 + l15;
#pragma unroll
      for (int r = 0; r < 4; ++r)
        C[(size_t)(row + r) * N + col] = (OutT)acc[m][n][r];
    }
  }
}

// ---------------- causal flash attention ----------------
// grid (T/128, H, B), 256 threads. Wave w owns 32 q-rows. KV tiles of 64.
// K tile LDS [64 kv][64 c], Vt tile LDS [64 d][64 kv], both XOR-swizzled (key=row&7).
__global__ __launch_bounds__(256) void k_attn(const bf16* __restrict__ Q,
                                              const bf16* __restrict__ Kg,
                                              const bf16* __restrict__ Vt,
                                              bf16* __restrict__ O) {
  __shared__ bf16 Ks[64*64];
  __shared__ bf16 Vs[64*64];
  __shared__ bf16 Ps[4][32*80];   // per-wave P scratch, row stride 80 (160B, 16B-aligned)

  const int tid  = threadIdx.x;
  const int lane = tid & 63;
  const int wave = tid >> 6;
  const int l15 = lane & 15;
  const int l4  = lane >> 4;
  const int b = blockIdx.z, h = blockIdx.y;
  const int q0 = blockIdx.x * 128;
  const int qw = q0 + wave * 32;

  // Q hoisted to registers: A-frags for rows qw..qw+31, k = D (2 ksteps of 32)
  bf16x8 qf[2][2];
#pragma unroll
  for (int m = 0; m < 2; ++m)
#pragma unroll
    for (int ks = 0; ks < 2; ++ks)
      qf[m][ks] = *reinterpret_cast<const bf16x8*>(
          &Q[(size_t)(b*TSEQ + qw + m*16 + l15)*NE + h*HD + ks*32 + l4*8]);

  f32x4 o[2][4] = {};
  float mi[2][4], li[2][4];
#pragma unroll
  for (int m = 0; m < 2; ++m)
#pragma unroll
    for (int r = 0; r < 4; ++r) { mi[m][r] = -1e30f; li[m][r] = 0.f; }

  const int srow = tid >> 3;                         // 0..31
  const int scol = ((tid & 7) ^ (srow & 7)) * 8;     // pre-swizzled global column
  const bf16* kg = Kg + (size_t)(b*TSEQ + srow)*NE + h*HD + scol;
  const bf16* vg = Vt + ((size_t)(b*NH + h)*HD + srow)*TSEQ + scol;
  bf16* kl = Ks + tid*8;
  bf16* vl = Vs + tid*8;

  const int ntiles = blockIdx.x * 2 + 2;
  for (int t = 0; t < ntiles; ++t) {
    const int kv0 = t * 64;
    __syncthreads();
    gl_lds16(kg + (size_t)kv0*NE,        kl);
    gl_lds16(kg + (size_t)(kv0+32)*NE,   kl + 32*64);
    gl_lds16(vg + kv0,                   vl);
    gl_lds16(vg + kv0 + (size_t)32*TSEQ, vl + 32*64);
    __syncthreads();

    // S = Q K^T  (32 q x 64 kv per wave)
    f32x4 s[2][4] = {};
#pragma unroll
    for (int n = 0; n < 4; ++n) {
      const int krow = n*16 + l15;
      const int key = krow & 7;
      bf16x8 kf0 = *reinterpret_cast<const bf16x8*>(&Ks[krow*64 + ((l4    ) ^ key)*8]);
      bf16x8 kf1 = *reinterpret_cast<const bf16x8*>(&Ks[krow*64 + ((l4 + 4) ^ key)*8]);
#pragma unroll
      for (int m = 0; m < 2; ++m) {
        s[m][n] = MFMA16(qf[m][0], kf0, s[m][n]);
        s[m][n] = MFMA16(qf[m][1], kf1, s[m][n]);
      }
    }

    // scale + causal mask + online softmax (row = qw + m*16 + l4*4 + r, col = kv)
#pragma unroll
    for (int m = 0; m < 2; ++m) {
      float rmax[4] = {-1e30f, -1e30f, -1e30f, -1e30f};
#pragma unroll
      for (int n = 0; n < 4; ++n) {
        const int kv = kv0 + n*16 + l15;
#pragma unroll
        for (int r = 0; r < 4; ++r) {
          const int q = qw + m*16 + l4*4 + r;
          float v = s[m][n][r] * 0.125f;
          v = (kv <= q) ? v : -1e30f;
          s[m][n][r] = v;
          rmax[r] = fmaxf(rmax[r], v);
        }
      }
#pragma unroll
      for (int r = 0; r < 4; ++r) {
        float v = rmax[r];
        v = fmaxf(v, __shfl_xor(v, 1));
        v = fmaxf(v, __shfl_xor(v, 2));
        v = fmaxf(v, __shfl_xor(v, 4));
        v = fmaxf(v, __shfl_xor(v, 8));
        const float mnew = fmaxf(mi[m][r], v);
        const float corr = __expf(mi[m][r] - mnew);
        mi[m][r] = mnew;
        li[m][r] *= corr;
#pragma unroll
        for (int n2 = 0; n2 < 4; ++n2) o[m][n2][r] *= corr;
      }
      float rsum[4] = {0.f, 0.f, 0.f, 0.f};
#pragma unroll
      for (int n = 0; n < 4; ++n) {
#pragma unroll
        for (int r = 0; r < 4; ++r) {
          const float p = __expf(s[m][n][r] - mi[m][r]);
          rsum[r] += p;
          Ps[wave][(m*16 + l4*4 + r)*80 + n*16 + l15] = (bf16)p;  // C-layout -> LDS
        }
      }
#pragma unroll
      for (int r = 0; r < 4; ++r) {
        float v = rsum[r];
        v += __shfl_xor(v, 1);
        v += __shfl_xor(v, 2);
        v += __shfl_xor(v, 4);
        v += __shfl_xor(v, 8);
        li[m][r] += v;
      }
    }

    // O += P V   (P re-read as A-frags from LDS; same-wave DS ordering is in-order)
    bf16x8 pf[2][2];
#pragma unroll
    for (int m = 0; m < 2; ++m)
#pragma unroll
      for (int ks = 0; ks < 2; ++ks)
        pf[m][ks] = *reinterpret_cast<const bf16x8*>(
            &Ps[wave][(m*16 + l15)*80 + ks*32 + l4*8]);
#pragma unroll
    for (int n2 = 0; n2 < 4; ++n2) {
      const int vrow = n2*16 + l15;
      const int key = vrow & 7;
      bf16x8 vf0 = *reinterpret_cast<const bf16x8*>(&Vs[vrow*64 + ((l4    ) ^ key)*8]);
      bf16x8 vf1 = *reinterpret_cast<const bf16x8*>(&Vs[vrow*64 + ((l4 + 4) ^ key)*8]);
#pragma unroll
      for (int m = 0; m < 2; ++m) {
        o[m][n2] = MFMA16(pf[m][0], vf0, o[m][n2]);
        o[m][n2] = MFMA16(pf[m][1], vf1, o[m][n2]);
      }
    }
  }

  // epilogue: normalize and write att [b*T+t][h*64+d]
#pragma unroll
  for (int m = 0; m < 2; ++m)
#pragma unroll
    for (int r = 0; r < 4; ++r) {
      const float inv = 1.0f / li[m][r];
      const size_t row = (size_t)(b*TSEQ + qw + m*16 + l4*4 + r);
#pragma unroll
      for (int n2 = 0; n2 < 4; ++n2)
        O[row*NE + h*HD + n2*16 + l15] = (bf16)(o[m][n2][r] * inv);
    }
}

// ---------------- launch ----------------
extern "C" void kernel_launch(void* const* d_in, const int* in_sizes, int n_in,
                              void* d_out, int out_size, void* d_ws, size_t ws_size,
                              hipStream_t stream) {
  const float* x   = (const float*)d_in[0];
  const float* wq  = (const float*)d_in[1];
  const float* wk  = (const float*)d_in[2];
  const float* wv  = (const float*)d_in[3];
  const float* wp1 = (const float*)d_in[4];
  const float* wp2 = (const float*)d_in[5];
  float* out = (float*)d_out;

  char* ws = (char*)d_ws;
  const size_t MB = 1024ull * 1024ull;
  bf16* xb   = (bf16*)(ws + 0*MB);    // 8 MB  [4096][1024]
  bf16* wqT  = (bf16*)(ws + 8*MB);    // 2 MB  [1024 hd][1024 c]
  bf16* wkT  = (bf16*)(ws + 10*MB);
  bf16* wvT  = (bf16*)(ws + 12*MB);
  bf16* wp1T = (bf16*)(ws + 14*MB);   // [1024 c_out][1024 hd]
  bf16* wp2T = (bf16*)(ws + 16*MB);   // [1024 e][1024 c]
  bf16* Qb   = (bf16*)(ws + 18*MB);   // 8 MB [4096][1024]
  bf16* Kb   = (bf16*)(ws + 26*MB);
  bf16* Vb   = (bf16*)(ws + 34*MB);
  bf16* Vtb  = (bf16*)(ws + 42*MB);   // [b][h][d][t]
  bf16* attb = (bf16*)(ws + 50*MB);
  bf16* yb   = (bf16*)(ws + 58*MB);   // total 66 MB

  // casts / weight transposes
  k_cast<<<4096, 256, 0, stream>>>(x, xb, MTOK*NE/4);
  dim3 tg(16, 16);
  k_transpose_cast<<<tg, 256, 0, stream>>>(wq,  wqT,  1024, 1024);
  k_transpose_cast<<<tg, 256, 0, stream>>>(wk,  wkT,  1024, 1024);
  k_transpose_cast<<<tg, 256, 0, stream>>>(wv,  wvT,  1024, 1024);
  k_transpose_cast<<<tg, 256, 0, stream>>>(wp1, wp1T, 1024, 1024);
  k_transpose_cast<<<tg, 256, 0, stream>>>(wp2, wp2T, 1024, 1024);

  // QKV projections
  dim3 gg(NE/128, MTOK/128);  // (8, 32)
  k_gemm_bt<bf16><<<gg, 256, 0, stream>>>(xb, wqT, Qb, MTOK, NE, NE);
  k_gemm_bt<bf16><<<gg, 256, 0, stream>>>(xb, wkT, Kb, MTOK, NE, NE);
  k_gemm_bt<bf16><<<gg, 256, 0, stream>>>(xb, wvT, Vb, MTOK, NE, NE);

  // V transpose for PV operand
  k_transpose_v<<<dim3(TSEQ/64, NH, 2), 256, 0, stream>>>(Vb, Vtb);

  // causal flash attention
  k_attn<<<dim3(TSEQ/128, NH, 2), 256, 0, stream>>>(Qb, Kb, Vtb, attb);

  // output projections
  k_gemm_bt<bf16><<<gg, 256, 0, stream>>>(attb, wp1T, yb, MTOK, NE, NE);
  k_gemm_bt<float><<<gg, 256, 0, stream>>>(yb, wp2T, out, MTOK, NE, NE);
}

// Round 2
// 180.839 us; speedup vs baseline: 1.5983x; 1.5983x over previous
//
#include <hip/hip_runtime.h>
#include <hip/hip_bf16.h>
#include <stdint.h>

typedef __bf16 bf16;
typedef __bf16 bf16x4 __attribute__((ext_vector_type(4)));
typedef __bf16 bf16x8 __attribute__((ext_vector_type(8)));
typedef float  f32x4  __attribute__((ext_vector_type(4)));

#define MFMA16(a,b,c) __builtin_amdgcn_mfma_f32_16x16x32_bf16((a),(b),(c),0,0,0)

#define TSEQ 2048
#define NE   1024
#define NE3  3072
#define NH   16
#define HD   64
#define MTOK 4096   // BATCH*TSEQ

#if defined(__has_builtin)
#if __has_builtin(__builtin_amdgcn_exp2f)
#define EXP2F(x) __builtin_amdgcn_exp2f(x)
#else
#define EXP2F(x) exp2f(x)
#endif
#else
#define EXP2F(x) exp2f(x)
#endif

// async global->LDS, 16B per lane; LDS dest = wave-uniform base + lane*16
__device__ __forceinline__ void gl_lds16(const bf16* g, bf16* l) {
  __builtin_amdgcn_global_load_lds(
      (const __attribute__((address_space(1))) void*)g,
      (__attribute__((address_space(3))) void*)l,
      16, 0, 0);
}

// ---------------- cast f32 -> bf16 (vectorized) ----------------
__global__ void k_cast(const float* __restrict__ in, bf16* __restrict__ out, int n4) {
  int i = blockIdx.x * blockDim.x + threadIdx.x;
  if (i < n4) {
    float4 v = reinterpret_cast<const float4*>(in)[i];
    bf16x4 o = { (bf16)v.x, (bf16)v.y, (bf16)v.z, (bf16)v.w };
    reinterpret_cast<bf16x4*>(out)[i] = o;
  }
}

// ---------------- all weight transposes in one dispatch ----------------
// z<3: wq/wk/wv -> W3T rows z*1024..; z==3: wp1 -> Wp1T; z==4: wp2 -> Wp2T
__global__ void k_transpose_all(const float* __restrict__ wq, const float* __restrict__ wk,
                                const float* __restrict__ wv, const float* __restrict__ wp1,
                                const float* __restrict__ wp2,
                                bf16* __restrict__ W3T, bf16* __restrict__ Wp1T,
                                bf16* __restrict__ Wp2T) {
  __shared__ float tile[64][65];
  const int z = blockIdx.z;
  const float* in = (z == 0) ? wq : (z == 1) ? wk : (z == 2) ? wv : (z == 3) ? wp1 : wp2;
  bf16* out = (z < 3) ? (W3T + (size_t)z * 1024 * 1024) : (z == 3 ? Wp1T : Wp2T);
  const int r0 = blockIdx.y * 64, c0 = blockIdx.x * 64;
  const int lc = threadIdx.x & 63, lr0 = threadIdx.x >> 6;
#pragma unroll
  for (int i = 0; i < 16; ++i) {
    int lr = i*4 + lr0;
    tile[lr][lc] = in[(size_t)(r0 + lr) * 1024 + (c0 + lc)];
  }
  __syncthreads();
#pragma unroll
  for (int i = 0; i < 16; ++i) {
    int lr = i*4 + lr0;
    out[(size_t)(c0 + lr) * 1024 + (r0 + lc)] = (bf16)tile[lc][lr];
  }
}

// ---------------- V section of QKV [tok][3072] -> Vt [b][h][d][t] ----------------
__global__ void k_transpose_v(const bf16* __restrict__ V, bf16* __restrict__ Vt) {
  __shared__ bf16 tile[64][65];
  const int b = blockIdx.z, h = blockIdx.y, t0 = blockIdx.x * 64;
  const int lc = threadIdx.x & 63, lr0 = threadIdx.x >> 6;
#pragma unroll
  for (int i = 0; i < 16; ++i) {
    int lr = i*4 + lr0;  // t within tile
    tile[lr][lc] = V[(size_t)(b*TSEQ + t0 + lr)*NE3 + h*HD + lc];
  }
  __syncthreads();
#pragma unroll
  for (int i = 0; i < 16; ++i) {
    int lr = i*4 + lr0;  // d within head
    Vt[((size_t)(b*NH + h)*HD + lr)*TSEQ + t0 + lc] = tile[lc][lr];
  }
}

// ---------------- GEMM: C[M,N] = A[M,K] * Bt[N,K]^T ----------------
// BM=128, BN in {128,64}. 4 waves (2x2), 2-phase double-buffered LDS,
// global_load_lds(16) with pre-swizzled source column (both-sides XOR swizzle).
template<int BN, typename OutT>
__global__ __launch_bounds__(256) void k_gemm_bt(const bf16* __restrict__ A,
                                                 const bf16* __restrict__ Bt,
                                                 OutT* __restrict__ C,
                                                 const int M, const int N, const int K) {
  constexpr int NC = BN / 32;   // N-frags per wave (2 waves split BN)
  __shared__ bf16 As[2][128*32];
  __shared__ bf16 Bs[2][BN*32];
  const int tid  = threadIdx.x;
  const int lane = tid & 63;
  const int wave = tid >> 6;
  const int wr = (wave >> 1) * 64;
  const int wc = (wave & 1) * (BN/2);
  const int l15 = lane & 15;
  const int l4  = lane >> 4;
  const int bm = blockIdx.y * 128;
  const int bn = blockIdx.x * BN;

  const int srow = tid >> 2;                              // 0..63
  const int scol = ((tid & 3) ^ ((tid >> 3) & 3)) * 8;    // pre-swizzled source column
  const bf16* ag = A  + (size_t)(bm + srow) * K + scol;
  const bf16* bg = Bt + (size_t)(bn + srow) * K + scol;
  const int kx = (l4 ^ ((l15 >> 1) & 3)) * 8;             // swizzled k-chunk on read

  f32x4 acc[4][NC] = {};

  auto stage = [&](int buf, int k0) {
    bf16* al = As[buf] + tid * 8;
    bf16* bl = Bs[buf] + tid * 8;
    gl_lds16(ag + k0,                   al);
    gl_lds16(ag + k0 + (size_t)64 * K,  al + 64*32);
    gl_lds16(bg + k0,                   bl);
    if (BN == 128) gl_lds16(bg + k0 + (size_t)64 * K, bl + 64*32);
  };

  stage(0, 0);
  __syncthreads();
  int cur = 0;
  for (int k0 = 0; k0 < K; k0 += 32) {
    if (k0 + 32 < K) stage(cur ^ 1, k0 + 32);   // prefetch next K-step
    bf16x8 af[4], bfr[NC];
#pragma unroll
    for (int m = 0; m < 4; ++m)
      af[m] = *reinterpret_cast<const bf16x8*>(&As[cur][(wr + m*16 + l15)*32 + kx]);
#pragma unroll
    for (int n = 0; n < NC; ++n)
      bfr[n] = *reinterpret_cast<const bf16x8*>(&Bs[cur][(wc + n*16 + l15)*32 + kx]);
#pragma unroll
    for (int m = 0; m < 4; ++m)
#pragma unroll
      for (int n = 0; n < NC; ++n)
        acc[m][n] = MFMA16(af[m], bfr[n], acc[m][n]);
    __syncthreads();   // drains prefetch vmcnt + protects buffer reuse
    cur ^= 1;
  }

#pragma unroll
  for (int m = 0; m < 4; ++m) {
    const int row = bm + wr + m*16 + l4*4;
#pragma unroll
    for (int n = 0; n < NC; ++n) {
      const int col = bn + wc + n*16 + l15;
#pragma unroll
      for (int r = 0; r < 4; ++r)
        C[(size_t)(row + r) * N + col] = (OutT)acc[m][n][r];
    }
  }
}

// ---------------- causal flash attention — barrier-free, wave-independent ----------------
// Each wave owns one 32-row q-tile. Swapped QK^T (mfma(K,Q) -> S^T, lane-local softmax
// rows at q=l15). K and V fetched global->reg, ping-pong prefetched. KVBLK=32.
// P routed through per-wave Ps LDS (stride 40 elems, 2-way-conflict layout).
struct KVr { bf16x8 kf[2][2]; bf16x8 vf[4]; };

__global__ __launch_bounds__(256) void k_attn(const bf16* __restrict__ QKV,
                                              const bf16* __restrict__ Vt,
                                              bf16* __restrict__ O) {
  __shared__ bf16 Ps[4][32*40];
  const int tid  = threadIdx.x;
  const int lane = tid & 63;
  const int wave = tid >> 6;
  const int l15 = lane & 15;
  const int l4  = lane >> 4;

  const int x   = blockIdx.x;       // 0..511
  const int lidx = x >> 5;          // 0..15, heavy-first ordering
  const int bh  = x & 31;
  const int b   = bh >> 4, h = bh & 15;
  const int qt  = (15 - lidx) * 4 + wave;   // q-tile 0..63 (first blocks get heaviest)
  const int q0  = qt * 32;
  const int nt  = qt + 1;           // KV tiles of 32

  const bf16* Qb = QKV + (size_t)b*TSEQ*NE3 +        h*HD;
  const bf16* Kb = QKV + (size_t)b*TSEQ*NE3 + 1024 + h*HD;
  const bf16* Vb = Vt  + (size_t)bh*HD*TSEQ;
  bf16* myPs = Ps[wave];

  // Q as B-frags (col=q=l15, k=c=l4*8+j), 2 q-frags x 2 k-steps
  bf16x8 qf[2][2];
#pragma unroll
  for (int qi = 0; qi < 2; ++qi)
#pragma unroll
    for (int ks = 0; ks < 2; ++ks)
      qf[qi][ks] = *reinterpret_cast<const bf16x8*>(
          &Qb[(size_t)(q0 + qi*16 + l15)*NE3 + ks*32 + l4*8]);

  f32x4 o[2][4] = {};                       // O[q=qi*16+l4*4+r][d=n2*16+l15]
  float m_run[2] = {-1e30f, -1e30f};
  float l_run[2] = {0.f, 0.f};
  const float SC = 0.125f * 1.44269504f;    // 1/sqrt(64) * log2(e)

  auto loadT = [&](KVr& R, int t) {
#pragma unroll
    for (int kvf = 0; kvf < 2; ++kvf)
#pragma unroll
      for (int ks = 0; ks < 2; ++ks)
        R.kf[kvf][ks] = *reinterpret_cast<const bf16x8*>(
            &Kb[(size_t)(t*32 + kvf*16 + l15)*NE3 + ks*32 + l4*8]);
#pragma unroll
    for (int n2 = 0; n2 < 4; ++n2)
      R.vf[n2] = *reinterpret_cast<const bf16x8*>(
          &Vb[(size_t)(n2*16 + l15)*TSEQ + t*32 + l4*8]);
  };

  auto tileCompute = [&](const KVr& R, int t) {
    // S^T[kv][q]: A=K (row=kv=l15, k=c), B=Q (col=q=l15, k=c)
    f32x4 st[2][2] = {};
#pragma unroll
    for (int ks = 0; ks < 2; ++ks)
#pragma unroll
      for (int kvf = 0; kvf < 2; ++kvf)
#pragma unroll
        for (int qi = 0; qi < 2; ++qi)
          st[kvf][qi] = MFMA16(R.kf[kvf][ks], qf[qi][ks], st[kvf][qi]);

    const bool diag = (t == nt - 1);
#pragma unroll
    for (int qi = 0; qi < 2; ++qi) {
      float ss[2][4];
#pragma unroll
      for (int kvf = 0; kvf < 2; ++kvf)
#pragma unroll
        for (int r = 0; r < 4; ++r) {
          float v = st[kvf][qi][r] * SC;
          if (diag && (kvf*16 + l4*4 + r > qi*16 + l15)) v = -1e30f;
          ss[kvf][r] = v;
        }
      float mx = ss[0][0];
#pragma unroll
      for (int kvf = 0; kvf < 2; ++kvf)
#pragma unroll
        for (int r = 0; r < 4; ++r) mx = fmaxf(mx, ss[kvf][r]);
      mx = fmaxf(mx, __shfl_xor(mx, 16));
      mx = fmaxf(mx, __shfl_xor(mx, 32));
      const float mnew = fmaxf(m_run[qi], mx);
      const float corr = EXP2F(m_run[qi] - mnew);
      m_run[qi] = mnew;

      float rs = 0.f;
#pragma unroll
      for (int kvf = 0; kvf < 2; ++kvf)
#pragma unroll
        for (int r = 0; r < 4; ++r) {
          const float p = EXP2F(ss[kvf][r] - mnew);
          rs += p;
          myPs[(qi*16 + l15)*40 + kvf*16 + l4*4 + r] = (bf16)p;
        }
      rs += __shfl_xor(rs, 16);
      rs += __shfl_xor(rs, 32);
      l_run[qi] = l_run[qi]*corr + rs;

      // rescale O (corr lives at q=l15; O rows are q=l4*4+r -> broadcast)
#pragma unroll
      for (int r = 0; r < 4; ++r) {
        const float cr = __shfl(corr, l4*4 + r);
#pragma unroll
        for (int n2 = 0; n2 < 4; ++n2) o[qi][n2][r] *= cr;
      }
    }

    // O += P V : A=P from Ps (row=q=l15, k=kv=l4*8+j), B=V (col=d=l15, k=kv)
    bf16x8 pa[2];
#pragma unroll
    for (int qi = 0; qi < 2; ++qi)
      pa[qi] = *reinterpret_cast<const bf16x8*>(&myPs[(qi*16 + l15)*40 + l4*8]);
#pragma unroll
    for (int qi = 0; qi < 2; ++qi)
#pragma unroll
      for (int n2 = 0; n2 < 4; ++n2)
        o[qi][n2] = MFMA16(pa[qi], R.vf[n2], o[qi][n2]);
  };

  KVr A, B;
  loadT(A, 0);
  int t = 0;
  while (true) {
    if (t + 1 < nt) loadT(B, t + 1);
    tileCompute(A, t);
    if (++t == nt) break;
    if (t + 1 < nt) loadT(A, t + 1);
    tileCompute(B, t);
    if (++t == nt) break;
  }

  // epilogue: divide by l (lives at q=l15 -> broadcast to q=l4*4+r rows) and store
#pragma unroll
  for (int qi = 0; qi < 2; ++qi) {
    const float rl = 1.f / l_run[qi];
#pragma unroll
    for (int r = 0; r < 4; ++r) {
      const float lr = __shfl(rl, l4*4 + r);
      const size_t row = (size_t)(b*TSEQ + q0 + qi*16 + l4*4 + r);
#pragma unroll
      for (int n2 = 0; n2 < 4; ++n2)
        O[row*NE + h*HD + n2*16 + l15] = (bf16)(o[qi][n2][r] * lr);
    }
  }
}

// ---------------- launch ----------------
extern "C" void kernel_launch(void* const* d_in, const int* in_sizes, int n_in,
                              void* d_out, int out_size, void* d_ws, size_t ws_size,
                              hipStream_t stream) {
  const float* x   = (const float*)d_in[0];
  const float* wq  = (const float*)d_in[1];
  const float* wk  = (const float*)d_in[2];
  const float* wv  = (const float*)d_in[3];
  const float* wp1 = (const float*)d_in[4];
  const float* wp2 = (const float*)d_in[5];
  float* out = (float*)d_out;

  char* ws = (char*)d_ws;
  const size_t MB = 1024ull * 1024ull;
  bf16* xb   = (bf16*)(ws + 0*MB);    // 8 MB  [4096][1024]
  bf16* W3T  = (bf16*)(ws + 8*MB);    // 6 MB  [3072][1024]  (wqT|wkT|wvT)
  bf16* wp1T = (bf16*)(ws + 14*MB);   // 2 MB
  bf16* wp2T = (bf16*)(ws + 16*MB);   // 2 MB
  bf16* QKVb = (bf16*)(ws + 18*MB);   // 24 MB [4096][3072]
  bf16* Vtb  = (bf16*)(ws + 42*MB);   // 8 MB  [b][h][d][t]
  bf16* attb = (bf16*)(ws + 50*MB);   // 8 MB  [4096][1024]
  bf16* yb   = (bf16*)(ws + 58*MB);   // 8 MB  (total 66 MB)

  k_cast<<<4096, 256, 0, stream>>>(x, xb, MTOK*NE/4);
  k_transpose_all<<<dim3(16, 16, 5), 256, 0, stream>>>(wq, wk, wv, wp1, wp2,
                                                       W3T, wp1T, wp2T);

  // fused QKV projection: [4096,1024] x [3072,1024]^T -> [4096,3072]
  k_gemm_bt<128, bf16><<<dim3(24, 32), 256, 0, stream>>>(xb, W3T, QKVb, MTOK, NE3, NE);

  // V transpose for PV operand
  k_transpose_v<<<dim3(TSEQ/64, NH, 2), 256, 0, stream>>>(QKVb + 2048, Vtb);

  // causal flash attention (barrier-free)
  k_attn<<<dim3(512), 256, 0, stream>>>(QKVb, Vtb, attb);

  // output projections (128x64 tiles -> 512 blocks each)
  k_gemm_bt<64, bf16 ><<<dim3(16, 32), 256, 0, stream>>>(attb, wp1T, yb,  MTOK, NE, NE);
  k_gemm_bt<64, float><<<dim3(16, 32), 256, 0, stream>>>(yb,   wp2T, out, MTOK, NE, NE);
}

// Round 3
// 142.265 us; speedup vs baseline: 2.0317x; 1.2711x over previous
//
#include <hip/hip_runtime.h>
#include <hip/hip_bf16.h>
#include <stdint.h>

typedef __bf16 bf16;
typedef __bf16 bf16x4 __attribute__((ext_vector_type(4)));
typedef __bf16 bf16x8 __attribute__((ext_vector_type(8)));
typedef float  f32x4  __attribute__((ext_vector_type(4)));

#define MFMA16(a,b,c) __builtin_amdgcn_mfma_f32_16x16x32_bf16((a),(b),(c),0,0,0)

#define TSEQ 2048
#define NE   1024
#define NE3  3072
#define NH   16
#define HD   64
#define MTOK 4096   // BATCH*TSEQ

#if defined(__has_builtin)
#if __has_builtin(__builtin_amdgcn_exp2f)
#define EXP2F(x) __builtin_amdgcn_exp2f(x)
#else
#define EXP2F(x) exp2f(x)
#endif
#else
#define EXP2F(x) exp2f(x)
#endif

// async global->LDS, 16B per lane; LDS dest = wave-uniform base + lane*16
__device__ __forceinline__ void gl_lds16(const bf16* g, bf16* l) {
  __builtin_amdgcn_global_load_lds(
      (const __attribute__((address_space(1))) void*)g,
      (__attribute__((address_space(3))) void*)l,
      16, 0, 0);
}

// ---------------- cast f32 -> bf16 (vectorized) ----------------
__global__ void k_cast(const float* __restrict__ in, bf16* __restrict__ out, int n4) {
  int i = blockIdx.x * blockDim.x + threadIdx.x;
  if (i < n4) {
    float4 v = reinterpret_cast<const float4*>(in)[i];
    bf16x4 o = { (bf16)v.x, (bf16)v.y, (bf16)v.z, (bf16)v.w };
    reinterpret_cast<bf16x4*>(out)[i] = o;
  }
}

// ---------------- all weight transposes in one dispatch ----------------
__global__ void k_transpose_all(const float* __restrict__ wq, const float* __restrict__ wk,
                                const float* __restrict__ wv, const float* __restrict__ wp1,
                                const float* __restrict__ wp2,
                                bf16* __restrict__ W3T, bf16* __restrict__ Wp1T,
                                bf16* __restrict__ Wp2T) {
  __shared__ float tile[64][65];
  const int z = blockIdx.z;
  const float* in = (z == 0) ? wq : (z == 1) ? wk : (z == 2) ? wv : (z == 3) ? wp1 : wp2;
  bf16* out = (z < 3) ? (W3T + (size_t)z * 1024 * 1024) : (z == 3 ? Wp1T : Wp2T);
  const int r0 = blockIdx.y * 64, c0 = blockIdx.x * 64;
  const int lc = threadIdx.x & 63, lr0 = threadIdx.x >> 6;
#pragma unroll
  for (int i = 0; i < 16; ++i) {
    int lr = i*4 + lr0;
    tile[lr][lc] = in[(size_t)(r0 + lr) * 1024 + (c0 + lc)];
  }
  __syncthreads();
#pragma unroll
  for (int i = 0; i < 16; ++i) {
    int lr = i*4 + lr0;
    out[(size_t)(c0 + lr) * 1024 + (r0 + lc)] = (bf16)tile[lc][lr];
  }
}

// ---------------- V section of QKV [tok][3072] -> Vt [b][h][d][t] ----------------
__global__ void k_transpose_v(const bf16* __restrict__ V, bf16* __restrict__ Vt) {
  __shared__ bf16 tile[64][65];
  const int b = blockIdx.z, h = blockIdx.y, t0 = blockIdx.x * 64;
  const int lc = threadIdx.x & 63, lr0 = threadIdx.x >> 6;
#pragma unroll
  for (int i = 0; i < 16; ++i) {
    int lr = i*4 + lr0;  // t within tile
    tile[lr][lc] = V[(size_t)(b*TSEQ + t0 + lr)*NE3 + h*HD + lc];
  }
  __syncthreads();
#pragma unroll
  for (int i = 0; i < 16; ++i) {
    int lr = i*4 + lr0;  // d within head
    Vt[((size_t)(b*NH + h)*HD + lr)*TSEQ + t0 + lc] = tile[lc][lr];
  }
}

// ---------------- GEMM: C[M,N] = A[M,K] * Bt[N,K]^T (unchanged from R2) ----------------
template<int BN, typename OutT>
__global__ __launch_bounds__(256) void k_gemm_bt(const bf16* __restrict__ A,
                                                 const bf16* __restrict__ Bt,
                                                 OutT* __restrict__ C,
                                                 const int M, const int N, const int K) {
  constexpr int NC = BN / 32;
  __shared__ bf16 As[2][128*32];
  __shared__ bf16 Bs[2][BN*32];
  const int tid  = threadIdx.x;
  const int lane = tid & 63;
  const int wave = tid >> 6;
  const int wr = (wave >> 1) * 64;
  const int wc = (wave & 1) * (BN/2);
  const int l15 = lane & 15;
  const int l4  = lane >> 4;
  const int bm = blockIdx.y * 128;
  const int bn = blockIdx.x * BN;

  const int srow = tid >> 2;
  const int scol = ((tid & 3) ^ ((tid >> 3) & 3)) * 8;
  const bf16* ag = A  + (size_t)(bm + srow) * K + scol;
  const bf16* bg = Bt + (size_t)(bn + srow) * K + scol;
  const int kx = (l4 ^ ((l15 >> 1) & 3)) * 8;

  f32x4 acc[4][NC] = {};

  auto stage = [&](int buf, int k0) {
    bf16* al = As[buf] + tid * 8;
    bf16* bl = Bs[buf] + tid * 8;
    gl_lds16(ag + k0,                   al);
    gl_lds16(ag + k0 + (size_t)64 * K,  al + 64*32);
    gl_lds16(bg + k0,                   bl);
    if (BN == 128) gl_lds16(bg + k0 + (size_t)64 * K, bl + 64*32);
  };

  stage(0, 0);
  __syncthreads();
  int cur = 0;
  for (int k0 = 0; k0 < K; k0 += 32) {
    if (k0 + 32 < K) stage(cur ^ 1, k0 + 32);
    bf16x8 af[4], bfr[NC];
#pragma unroll
    for (int m = 0; m < 4; ++m)
      af[m] = *reinterpret_cast<const bf16x8*>(&As[cur][(wr + m*16 + l15)*32 + kx]);
#pragma unroll
    for (int n = 0; n < NC; ++n)
      bfr[n] = *reinterpret_cast<const bf16x8*>(&Bs[cur][(wc + n*16 + l15)*32 + kx]);
#pragma unroll
    for (int m = 0; m < 4; ++m)
#pragma unroll
      for (int n = 0; n < NC; ++n)
        acc[m][n] = MFMA16(af[m], bfr[n], acc[m][n]);
    __syncthreads();
    cur ^= 1;
  }

#pragma unroll
  for (int m = 0; m < 4; ++m) {
    const int row = bm + wr + m*16 + l4*4;
#pragma unroll
    for (int n = 0; n < NC; ++n) {
      const int col = bn + wc + n*16 + l15;
#pragma unroll
      for (int r = 0; r < 4; ++r)
        C[(size_t)(row + r) * N + col] = (OutT)acc[m][n][r];
    }
  }
}

// ---------------- causal flash attention, LDS-shared K/V ----------------
// 4 waves x 32 q-rows = 128 q-rows per block. KVBLK=64, double-buffered LDS.
// K/V stored as [2 ks-panels][64 rows][32 elems] (64B rows, m97 granule swizzle).
// S^T = mfma(K,Q); O^T accumulation (corr & 1/l lane-local); T13 defer-max;
// l-reduction deferred to epilogue; Q pre-scaled by 0.125*log2e.
__global__ __launch_bounds__(256) void k_attn(const bf16* __restrict__ QKV,
                                              const bf16* __restrict__ Vt,
                                              bf16* __restrict__ O) {
  __shared__ bf16 Ks[2][2*64*32];     // [buf][ks][row][32]
  __shared__ bf16 Vs[2][2*64*32];     // [buf][ks2][d][32]
  __shared__ bf16 Ps[4][2*32*32];     // [wave][ks2][q][32]

  const int tid  = threadIdx.x;
  const int lane = tid & 63;
  const int wave = tid >> 6;
  const int l15 = lane & 15;
  const int l4  = lane >> 4;

  const int x  = blockIdx.x;          // 0..511, heavy-first
  const int qb = 15 - (x >> 5);
  const int bh = x & 31;
  const int b  = bh >> 4, h = bh & 15;
  const int qw = qb * 128 + wave * 32;      // this wave's first q row
  const int nt = 2 * qb + 2;                // 64-kv tiles

  const bf16* Qb = QKV + (size_t)b*TSEQ*NE3 +        h*HD;
  const bf16* Kb = QKV + (size_t)b*TSEQ*NE3 + 1024 + h*HD;
  const bf16* Vb = Vt  + (size_t)bh*HD*TSEQ;
  bf16* Pw = Ps[wave];

  const float SC = 0.125f * 1.44269504f;
  // Q as B-frags, pre-scaled
  bf16x8 qf[2][2];
#pragma unroll
  for (int qi = 0; qi < 2; ++qi)
#pragma unroll
    for (int ks = 0; ks < 2; ++ks) {
      bf16x8 qv = *reinterpret_cast<const bf16x8*>(
          &Qb[(size_t)(qw + qi*16 + l15)*NE3 + ks*32 + l4*8]);
#pragma unroll
      for (int j = 0; j < 8; ++j) qv[j] = (bf16)((float)qv[j] * SC);
      qf[qi][ks] = qv;
    }

  f32x4 ot[2][4] = {};                 // O^T: row d = n2*16+l4*4+r, col q = qi*16+l15
  float m_run[2] = {-1e30f, -1e30f};
  float l_part[2] = {0.f, 0.f};

  // staging map: thread -> (row = tid>>2, granule = tid&3), source granule pre-swizzled
  const int srow = tid >> 2;                       // 0..63
  const int sg   = ((tid & 3) ^ ((tid >> 3) & 3)); // source 8-elem granule
  const int swz  = (l4 ^ ((l15 >> 1) & 3)) * 8;    // read-side swizzled column (elems)

  auto stage = [&](int buf, int t) {
#pragma unroll
    for (int ks = 0; ks < 2; ++ks)
      gl_lds16(&Kb[(size_t)(t*64 + srow)*NE3 + ks*32 + sg*8], &Ks[buf][ks*2048 + tid*8]);
#pragma unroll
    for (int ks = 0; ks < 2; ++ks)
      gl_lds16(&Vb[(size_t)srow*TSEQ + t*64 + ks*32 + sg*8],  &Vs[buf][ks*2048 + tid*8]);
  };

  stage(0, 0);
  __syncthreads();
  int cur = 0;

  for (int t = 0; t < nt; ++t) {
    if (t + 1 < nt) stage(cur ^ 1, t + 1);

    if (t*64 <= qw + 31) {             // skip fully-masked tiles
      // S^T[kv][q] = K Q^T
      f32x4 st[2][4] = {};
#pragma unroll
      for (int kvf = 0; kvf < 4; ++kvf) {
        const int row = kvf*16 + l15;
#pragma unroll
        for (int ks = 0; ks < 2; ++ks) {
          bf16x8 kf = *reinterpret_cast<const bf16x8*>(&Ks[cur][ks*2048 + row*32 + swz]);
          st[0][kvf] = MFMA16(kf, qf[0][ks], st[0][kvf]);
          st[1][kvf] = MFMA16(kf, qf[1][ks], st[1][kvf]);
        }
      }

      const bool maskNeeded = (t*64 + 63 > qw);
#pragma unroll
      for (int qi = 0; qi < 2; ++qi) {
        const int q = qw + qi*16 + l15;
        if (maskNeeded) {
#pragma unroll
          for (int kvf = 0; kvf < 4; ++kvf)
#pragma unroll
            for (int r = 0; r < 4; ++r)
              if (t*64 + kvf*16 + l4*4 + r > q) st[qi][kvf][r] = -1e30f;
        }
        float mx = st[qi][0][0];
#pragma unroll
        for (int kvf = 0; kvf < 4; ++kvf)
#pragma unroll
          for (int r = 0; r < 4; ++r) mx = fmaxf(mx, st[qi][kvf][r]);
        mx = fmaxf(mx, __shfl_xor(mx, 16));
        mx = fmaxf(mx, __shfl_xor(mx, 32));

        if (__any(mx > m_run[qi] + 8.f)) {       // T13 defer-max
          const float mnew = fmaxf(m_run[qi], mx);
          const float corr = EXP2F(m_run[qi] - mnew);
          l_part[qi] *= corr;
#pragma unroll
          for (int n2 = 0; n2 < 4; ++n2) ot[qi][n2] *= corr;
          m_run[qi] = mnew;
        }

        float rs = 0.f;
#pragma unroll
        for (int kvf = 0; kvf < 4; ++kvf) {
          bf16x4 pk;
#pragma unroll
          for (int r = 0; r < 4; ++r) {
            const float p = EXP2F(st[qi][kvf][r] - m_run[qi]);
            rs += p;
            pk[r] = (bf16)p;
          }
          const int gp = (((kvf & 1)*2 + (l4 >> 1)) ^ ((l15 >> 1) & 3));
          *reinterpret_cast<bf16x4*>(
              &Pw[(kvf>>1)*1024 + (qi*16 + l15)*32 + gp*8 + (l4 & 1)*4]) = pk;
        }
        l_part[qi] += rs;
      }

      // O^T += V^T P^T
      bf16x8 pa[2][2];
#pragma unroll
      for (int qi = 0; qi < 2; ++qi)
#pragma unroll
        for (int ks = 0; ks < 2; ++ks)
          pa[qi][ks] = *reinterpret_cast<const bf16x8*>(
              &Pw[ks*1024 + (qi*16 + l15)*32 + swz]);
#pragma unroll
      for (int n2 = 0; n2 < 4; ++n2) {
        const int vrow = n2*16 + l15;
#pragma unroll
        for (int ks = 0; ks < 2; ++ks) {
          bf16x8 vf = *reinterpret_cast<const bf16x8*>(&Vs[cur][ks*2048 + vrow*32 + swz]);
          ot[0][n2] = MFMA16(vf, pa[0][ks], ot[0][n2]);
          ot[1][n2] = MFMA16(vf, pa[1][ks], ot[1][n2]);
        }
      }
    }

    __syncthreads();
    cur ^= 1;
  }

  // epilogue: reduce l across l4 groups (lane-local col q), normalize, store
#pragma unroll
  for (int qi = 0; qi < 2; ++qi) {
    float l = l_part[qi];
    l += __shfl_xor(l, 16);
    l += __shfl_xor(l, 32);
    const float rl = 1.f / l;
    const size_t row = (size_t)(b*TSEQ + qw + qi*16 + l15);
#pragma unroll
    for (int n2 = 0; n2 < 4; ++n2) {
      bf16x4 ov;
#pragma unroll
      for (int r = 0; r < 4; ++r) ov[r] = (bf16)(ot[qi][n2][r] * rl);
      *reinterpret_cast<bf16x4*>(&O[row*NE + h*HD + n2*16 + l4*4]) = ov;
    }
  }
}

// ---------------- launch ----------------
extern "C" void kernel_launch(void* const* d_in, const int* in_sizes, int n_in,
                              void* d_out, int out_size, void* d_ws, size_t ws_size,
                              hipStream_t stream) {
  const float* x   = (const float*)d_in[0];
  const float* wq  = (const float*)d_in[1];
  const float* wk  = (const float*)d_in[2];
  const float* wv  = (const float*)d_in[3];
  const float* wp1 = (const float*)d_in[4];
  const float* wp2 = (const float*)d_in[5];
  float* out = (float*)d_out;

  char* ws = (char*)d_ws;
  const size_t MB = 1024ull * 1024ull;
  bf16* xb   = (bf16*)(ws + 0*MB);    // 8 MB
  bf16* W3T  = (bf16*)(ws + 8*MB);    // 6 MB
  bf16* wp1T = (bf16*)(ws + 14*MB);   // 2 MB
  bf16* wp2T = (bf16*)(ws + 16*MB);   // 2 MB
  bf16* QKVb = (bf16*)(ws + 18*MB);   // 24 MB
  bf16* Vtb  = (bf16*)(ws + 42*MB);   // 8 MB
  bf16* attb = (bf16*)(ws + 50*MB);   // 8 MB
  bf16* yb   = (bf16*)(ws + 58*MB);   // 8 MB

  k_cast<<<4096, 256, 0, stream>>>(x, xb, MTOK*NE/4);
  k_transpose_all<<<dim3(16, 16, 5), 256, 0, stream>>>(wq, wk, wv, wp1, wp2,
                                                       W3T, wp1T, wp2T);

  k_gemm_bt<128, bf16><<<dim3(24, 32), 256, 0, stream>>>(xb, W3T, QKVb, MTOK, NE3, NE);

  k_transpose_v<<<dim3(TSEQ/64, NH, 2), 256, 0, stream>>>(QKVb + 2048, Vtb);

  k_attn<<<dim3(512), 256, 0, stream>>>(QKVb, Vtb, attb);

  k_gemm_bt<64, bf16 ><<<dim3(16, 32), 256, 0, stream>>>(attb, wp1T, yb,  MTOK, NE, NE);
  k_gemm_bt<64, float><<<dim3(16, 32), 256, 0, stream>>>(yb,   wp2T, out, MTOK, NE, NE);
}